// Round 3
// baseline (2368.400 us; speedup 1.0000x reference)
//
#include <hip/hip_runtime.h>

// b=64, c=d=512, hw=4096, n=32, M=b*n=2048, 3 slot-attention iterations.
// Round 3 = Round 2 structure with the const-correctness fix on k_gemm1's stats arg.
//  - qgemm: n-split (no atomics), full-K, bias fused, BN1 partial stats in epilogue
//  - gemm1: dbuf (prefetch-before-compute, 1 barrier/tile), BN1 apply fused into
//           A-staging, BN2 partial stats fused into epilogue
//  - gemm2: dbuf, BN2 apply + relu + rowsum partials fused into A-staging,
//           atomic-free partial outputs + finout reduce/divide

#define F4(p)  (*reinterpret_cast<float4*>(p))
#define CF4(p) (*reinterpret_cast<const float4*>(p))

// stats buffer float offsets
#define O_SUM1 0
#define O_SQ1  512
#define O_SUM2 1024
#define O_SQ2  1056
#define O_SC1  1088
#define O_SH1  1600
#define O_SC2  2112
#define O_SH2  2144
#define O_RS   2176   // rowsum[2048]

typedef __attribute__((address_space(1))) const void gvoid_t;
typedef __attribute__((address_space(3))) void lvoid_t;
__device__ __forceinline__ void gload_lds16(const float* g, float* l) {
    // async global->LDS, 16B/lane; LDS dest = wave-uniform base + lane*16
    __builtin_amdgcn_global_load_lds((gvoid_t*)g, (lvoid_t*)l, 16, 0, 0);
}

// ---------------- one-time 64x64-tile transpose: A[R][C] -> AT[C][R] ----------------
__global__ __launch_bounds__(256) void k_transpose64(const float* __restrict__ A,
                                                     float* __restrict__ AT,
                                                     int R, int C) {
    __shared__ __align__(16) float tile[64][68];
    const int cb = blockIdx.x * 64;
    const int rb = blockIdx.y * 64;
    const size_t bofs = (size_t)blockIdx.z * R * C;
    const float* Ab = A + bofs;
    float* ATb = AT + bofs;
    const int t = threadIdx.x;
    const int g = t >> 4, h = t & 15;
    float4 v0 = CF4(Ab + (size_t)(rb + g * 4 + 0) * C + cb + h * 4);
    float4 v1 = CF4(Ab + (size_t)(rb + g * 4 + 1) * C + cb + h * 4);
    float4 v2 = CF4(Ab + (size_t)(rb + g * 4 + 2) * C + cb + h * 4);
    float4 v3 = CF4(Ab + (size_t)(rb + g * 4 + 3) * C + cb + h * 4);
    float4 w0 = {v0.x, v1.x, v2.x, v3.x};
    float4 w1 = {v0.y, v1.y, v2.y, v3.y};
    float4 w2 = {v0.z, v1.z, v2.z, v3.z};
    float4 w3 = {v0.w, v1.w, v2.w, v3.w};
    F4(&tile[h * 4 + 0][g * 4]) = w0;
    F4(&tile[h * 4 + 1][g * 4]) = w1;
    F4(&tile[h * 4 + 2][g * 4]) = w2;
    F4(&tile[h * 4 + 3][g * 4]) = w3;
    __syncthreads();
#pragma unroll
    for (int s = 0; s < 4; ++s) {
        int crow = g + 16 * s;
        F4(ATb + (size_t)(cb + crow) * R + rb + h * 4) = F4(&tile[crow][h * 4]);
    }
}

// ---------------- init / blend ----------------
__global__ void k_init_slots(const float* __restrict__ meta, float* __restrict__ slots) {
    int f = blockIdx.x * 256 + threadIdx.x;      // float4 index, 262144
    int m = f >> 7;
    int d4 = f & 127;
    F4(slots + (size_t)f * 4) = CF4(meta + ((size_t)((m & 31) << 7) + d4) * 4);
}

__global__ void k_blend(float* __restrict__ slots, const float* __restrict__ ns) {
    int f = blockIdx.x * 256 + threadIdx.x;
    float4 s = F4(slots + (size_t)f * 4);
    float4 n = CF4(ns + (size_t)f * 4);
    s.x = 0.9f * s.x + 0.1f * n.x;
    s.y = 0.9f * s.y + 0.1f * n.y;
    s.z = 0.9f * s.z + 0.1f * n.z;
    s.w = 0.9f * s.w + 0.1f * n.w;
    F4(slots + (size_t)f * 4) = s;
}

__global__ void k_zero_stats(float* __restrict__ stats) {
    int i = threadIdx.x;
#pragma unroll
    for (int s = 0; s < 4; ++s) stats[i + 256 * s] = 0.0f;   // O_SUM1..O_SQ1 (1024)
}

// ---------------- qgemm: q[m,n] = sum_k slots[m,k]*WqT[k,n] + bq[n] ----------------
// grid (128 m-tiles of 16, 2 n-splits of 256). Full K, no atomics on q.
// A staged once (16x512 -> asT[k][m]); B double-buffered via gload_lds.
// Epilogue: bias add, q write, BN1 partial column stats -> atomicAdd.
__global__ __launch_bounds__(256) void k_qgemm(const float* __restrict__ S,
                                               const float* __restrict__ WqT,
                                               const float* __restrict__ bq,
                                               float* __restrict__ Q,
                                               float* __restrict__ stats) {
    __shared__ __align__(16) float asT[512][16];     // [k][m] 32 KB, staged once
    __shared__ __align__(16) float bs[2][32][256];   // 64 KB dbuf
    __shared__ __align__(16) float ls[4][256], lq[4][256];   // 8 KB stats reduce
    const int m0 = blockIdx.x * 16;
    const int n0 = blockIdx.y * 256;
    const int t = threadIdx.x;
    const int w = t >> 6, l = t & 63;
    const int ty = w, tx = l;
    {   // A: slots[m0..+16][0..512] -> asT[k][m]
        int m = t & 15, fq = t >> 4;
#pragma unroll
        for (int s = 0; s < 8; ++s) {
            int k = fq * 4 + s * 64;
            float4 v = CF4(S + (size_t)(m0 + m) * 512 + k);
            asT[k + 0][m] = v.x; asT[k + 1][m] = v.y;
            asT[k + 2][m] = v.z; asT[k + 3][m] = v.w;
        }
    }
#pragma unroll
    for (int cc = 0; cc < 8; ++cc) {    // B tile 0
        int r = w * 8 + cc;
        gload_lds16(WqT + (size_t)r * 512 + n0 + l * 4, &bs[0][r][0]);
    }
    __syncthreads();
    float c[4][4] = {};
    int cur = 0;
    for (int tgl = 0; tgl < 16; ++tgl) {
        if (tgl < 15) {
            int k1 = (tgl + 1) * 32;
#pragma unroll
            for (int cc = 0; cc < 8; ++cc) {
                int r = w * 8 + cc;
                gload_lds16(WqT + (size_t)(k1 + r) * 512 + n0 + l * 4, &bs[cur ^ 1][r][0]);
            }
        }
        int k0 = tgl * 32;
#pragma unroll 8
        for (int k = 0; k < 32; ++k) {
            float4 a = F4(&asT[k0 + k][ty * 4]);
            float4 b = F4(&bs[cur][k][tx * 4]);
            float av[4] = {a.x, a.y, a.z, a.w};
            float bv[4] = {b.x, b.y, b.z, b.w};
#pragma unroll
            for (int ii = 0; ii < 4; ++ii)
#pragma unroll
                for (int jj = 0; jj < 4; ++jj)
                    c[ii][jj] = fmaf(av[ii], bv[jj], c[ii][jj]);
        }
        __syncthreads();
        cur ^= 1;
    }
    // epilogue: bias, write q, BN1 partial stats
    float4 bias = CF4(bq + n0 + tx * 4);
    float4 sv = {0.f, 0.f, 0.f, 0.f}, qv = {0.f, 0.f, 0.f, 0.f};
#pragma unroll
    for (int ii = 0; ii < 4; ++ii) {
        float4 v = {c[ii][0] + bias.x, c[ii][1] + bias.y,
                    c[ii][2] + bias.z, c[ii][3] + bias.w};
        F4(Q + (size_t)(m0 + ty * 4 + ii) * 512 + n0 + tx * 4) = v;
        sv.x += v.x; sv.y += v.y; sv.z += v.z; sv.w += v.w;
        qv.x += v.x * v.x; qv.y += v.y * v.y; qv.z += v.z * v.z; qv.w += v.w * v.w;
    }
    F4(&ls[ty][tx * 4]) = sv;
    F4(&lq[ty][tx * 4]) = qv;
    __syncthreads();
    {
        float s  = ls[0][t] + ls[1][t] + ls[2][t] + ls[3][t];
        float q2 = lq[0][t] + lq[1][t] + lq[2][t] + lq[3][t];
        atomicAdd(&stats[O_SUM1 + n0 + t], s);
        atomicAdd(&stats[O_SQ1 + n0 + t], q2);
    }
}

__global__ void k_bn1_fin(float* __restrict__ stats, const float* __restrict__ g1,
                          const float* __restrict__ b1) {
    int c = threadIdx.x;   // 512
    float mean = stats[O_SUM1 + c] * (1.0f / 2048.0f);
    float var = stats[O_SQ1 + c] * (1.0f / 2048.0f) - mean * mean;
    float sc = rsqrtf(var + 1e-5f) * g1[c];
    stats[O_SC1 + c] = sc;
    stats[O_SH1 + c] = b1[c] - mean * sc;
    if (c < 64) stats[O_SUM2 + c] = 0.0f;   // zero SUM2(32)+SQ2(32) for gemm1
}

// ---------------- GEMM1: attn[b,i,j] = sum_k relu(bn1(q))[b*32+i,k]*x[b,k,j] ----------------
// grid (8 j-tiles of 512, 64 b). Double-buffered; BN1+relu applied when staging A;
// epilogue: attn write + BN2 partial stats (wave shfl-reduce + atomicAdd).
// NOTE: stats is read-write here (reads SC1/SH1, atomics into SUM2/SQ2).
__global__ __launch_bounds__(256) void k_gemm1(const float* __restrict__ Q,
                                               const float* __restrict__ X,
                                               float* __restrict__ stats,
                                               float* __restrict__ attn) {
    __shared__ __align__(16) float qsT[2][32][36];   // [k][i] 9.2 KB
    __shared__ __align__(16) float xs[2][32][512];   // 128 KB dbuf
    const int b = blockIdx.y;
    const int j0 = blockIdx.x * 512;
    const int t = threadIdx.x;
    const int w = t >> 6, l = t & 63;
    const int ty = w, tx = l;
    const float* qb = Q + (size_t)b * 32 * 512;
    const float* xb = X + (size_t)b * 512 * 4096 + j0;
    const int ai = t >> 3, akq = t & 7;
    {   // prologue: tile 0
#pragma unroll
        for (int cc = 0; cc < 16; ++cc) {
            int chunk = w * 16 + cc;
            int row = chunk >> 1, half = chunk & 1;
            gload_lds16(xb + (size_t)row * 4096 + half * 256 + l * 4,
                        &xs[0][row][half * 256]);
        }
        float4 v = CF4(qb + (size_t)ai * 512 + akq * 4);
        float4 sc = CF4(stats + O_SC1 + akq * 4);
        float4 sh = CF4(stats + O_SH1 + akq * 4);
        v.x = fmaxf(fmaf(v.x, sc.x, sh.x), 0.f);
        v.y = fmaxf(fmaf(v.y, sc.y, sh.y), 0.f);
        v.z = fmaxf(fmaf(v.z, sc.z, sh.z), 0.f);
        v.w = fmaxf(fmaf(v.w, sc.w, sh.w), 0.f);
        qsT[0][akq * 4 + 0][ai] = v.x; qsT[0][akq * 4 + 1][ai] = v.y;
        qsT[0][akq * 4 + 2][ai] = v.z; qsT[0][akq * 4 + 3][ai] = v.w;
    }
    __syncthreads();
    float c[8][8] = {};
    int cur = 0;
    for (int tgl = 0; tgl < 16; ++tgl) {
        float4 va, vsc, vsh;
        const bool pf = tgl < 15;
        if (pf) {   // prefetch tile t+1: B async to LDS, A to regs
            int k1 = (tgl + 1) * 32;
#pragma unroll
            for (int cc = 0; cc < 16; ++cc) {
                int chunk = w * 16 + cc;
                int row = chunk >> 1, half = chunk & 1;
                gload_lds16(xb + (size_t)(k1 + row) * 4096 + half * 256 + l * 4,
                            &xs[cur ^ 1][row][half * 256]);
            }
            va  = CF4(qb + (size_t)ai * 512 + k1 + akq * 4);
            vsc = CF4(stats + O_SC1 + k1 + akq * 4);
            vsh = CF4(stats + O_SH1 + k1 + akq * 4);
        }
#pragma unroll 8
        for (int k = 0; k < 32; ++k) {
            float4 a0 = F4(&qsT[cur][k][ty * 8]);
            float4 a1 = F4(&qsT[cur][k][ty * 8 + 4]);
            float4 b0 = F4(&xs[cur][k][tx * 4]);
            float4 b1 = F4(&xs[cur][k][256 + tx * 4]);
            float av[8] = {a0.x, a0.y, a0.z, a0.w, a1.x, a1.y, a1.z, a1.w};
            float bv[8] = {b0.x, b0.y, b0.z, b0.w, b1.x, b1.y, b1.z, b1.w};
#pragma unroll
            for (int ii = 0; ii < 8; ++ii)
#pragma unroll
                for (int jj = 0; jj < 8; ++jj)
                    c[ii][jj] = fmaf(av[ii], bv[jj], c[ii][jj]);
        }
        if (pf) {   // BN1+relu, write A(t+1) into other buffer
            va.x = fmaxf(fmaf(va.x, vsc.x, vsh.x), 0.f);
            va.y = fmaxf(fmaf(va.y, vsc.y, vsh.y), 0.f);
            va.z = fmaxf(fmaf(va.z, vsc.z, vsh.z), 0.f);
            va.w = fmaxf(fmaf(va.w, vsc.w, vsh.w), 0.f);
            qsT[cur ^ 1][akq * 4 + 0][ai] = va.x;
            qsT[cur ^ 1][akq * 4 + 1][ai] = va.y;
            qsT[cur ^ 1][akq * 4 + 2][ai] = va.z;
            qsT[cur ^ 1][akq * 4 + 3][ai] = va.w;
        }
        __syncthreads();
        cur ^= 1;
    }
    // epilogue: write attn (raw) + BN2 partial stats per channel i
#pragma unroll
    for (int ii = 0; ii < 8; ++ii) {
        float* dst = attn + (size_t)(b * 32 + ty * 8 + ii) * 4096 + j0;
        float4 r0 = {c[ii][0], c[ii][1], c[ii][2], c[ii][3]};
        float4 r1 = {c[ii][4], c[ii][5], c[ii][6], c[ii][7]};
        F4(dst + tx * 4) = r0;
        F4(dst + 256 + tx * 4) = r1;
        float s  = r0.x + r0.y + r0.z + r0.w + r1.x + r1.y + r1.z + r1.w;
        float q2 = r0.x * r0.x + r0.y * r0.y + r0.z * r0.z + r0.w * r0.w +
                   r1.x * r1.x + r1.y * r1.y + r1.z * r1.z + r1.w * r1.w;
#pragma unroll
        for (int off = 32; off > 0; off >>= 1) {
            s  += __shfl_down(s, off, 64);
            q2 += __shfl_down(q2, off, 64);
        }
        if (tx == 0) {
            atomicAdd(&stats[O_SUM2 + ty * 8 + ii], s);
            atomicAdd(&stats[O_SQ2 + ty * 8 + ii], q2);
        }
    }
}

__global__ void k_bn2_fin(float* __restrict__ stats, const float* __restrict__ g2,
                          const float* __restrict__ b2) {
    int t = threadIdx.x;   // 256
    if (t < 32) {
        const float inv = 1.0f / 262144.0f;
        float mean = stats[O_SUM2 + t] * inv;
        float var = stats[O_SQ2 + t] * inv - mean * mean;
        float sc = rsqrtf(var + 1e-5f) * g2[t];
        stats[O_SC2 + t] = sc;
        stats[O_SH2 + t] = b2[t] - mean * sc;
    }
#pragma unroll
    for (int s = 0; s < 8; ++s) stats[O_RS + t + 256 * s] = 0.0f;   // zero rowsums
}

// ---------------- GEMM2: part[sp][b*32+i][d] = sum_{j in split} bn2relu(attn)[b,i,j]*xT[b,j,d] ----------------
// grid (4 j-splits of 1024, 64 b). Double-buffered; BN2+relu applied at A-staging,
// rowsum partials accumulated there (atomicAdd 32/block); atomic-free partial out.
__global__ __launch_bounds__(256) void k_gemm2(const float* __restrict__ attn,
                                               const float* __restrict__ XT,
                                               float* __restrict__ stats,
                                               float* __restrict__ part) {
    __shared__ __align__(16) float asT[2][32][36];   // [j][i]
    __shared__ __align__(16) float xs[2][32][512];   // [j][d] 128 KB dbuf
    const int b = blockIdx.y;
    const int sp = blockIdx.x;
    const int jbase0 = sp * 1024;
    const int t = threadIdx.x;
    const int w = t >> 6, l = t & 63;
    const int ty = w, tx = l;
    const float* ab = attn + (size_t)b * 32 * 4096 + jbase0;
    const float* xb = XT + (size_t)b * 4096 * 512 + (size_t)jbase0 * 512;
    const int ai = t >> 3, ajq = t & 7;
    const float scA = stats[O_SC2 + ai];
    const float shA = stats[O_SH2 + ai];
    float rsum = 0.f;
    {   // prologue: tile 0
#pragma unroll
        for (int cc = 0; cc < 16; ++cc) {
            int chunk = w * 16 + cc;
            int row = chunk >> 1, half = chunk & 1;
            gload_lds16(xb + (size_t)row * 512 + half * 256 + l * 4,
                        &xs[0][row][half * 256]);
        }
        float4 v = CF4(ab + (size_t)ai * 4096 + ajq * 4);
        v.x = fmaxf(fmaf(v.x, scA, shA), 0.f);
        v.y = fmaxf(fmaf(v.y, scA, shA), 0.f);
        v.z = fmaxf(fmaf(v.z, scA, shA), 0.f);
        v.w = fmaxf(fmaf(v.w, scA, shA), 0.f);
        rsum += v.x + v.y + v.z + v.w;
        asT[0][ajq * 4 + 0][ai] = v.x; asT[0][ajq * 4 + 1][ai] = v.y;
        asT[0][ajq * 4 + 2][ai] = v.z; asT[0][ajq * 4 + 3][ai] = v.w;
    }
    __syncthreads();
    float c[8][8] = {};
    int cur = 0;
    for (int tgl = 0; tgl < 32; ++tgl) {
        float4 va;
        const bool pf = tgl < 31;
        if (pf) {
            int jb = (tgl + 1) * 32;
#pragma unroll
            for (int cc = 0; cc < 16; ++cc) {
                int chunk = w * 16 + cc;
                int row = chunk >> 1, half = chunk & 1;
                gload_lds16(xb + (size_t)(jb + row) * 512 + half * 256 + l * 4,
                            &xs[cur ^ 1][row][half * 256]);
            }
            va = CF4(ab + (size_t)ai * 4096 + jb + ajq * 4);
        }
#pragma unroll 8
        for (int k = 0; k < 32; ++k) {
            float4 a0 = F4(&asT[cur][k][ty * 8]);
            float4 a1 = F4(&asT[cur][k][ty * 8 + 4]);
            float4 b0 = F4(&xs[cur][k][tx * 4]);
            float4 b1 = F4(&xs[cur][k][256 + tx * 4]);
            float av[8] = {a0.x, a0.y, a0.z, a0.w, a1.x, a1.y, a1.z, a1.w};
            float bv[8] = {b0.x, b0.y, b0.z, b0.w, b1.x, b1.y, b1.z, b1.w};
#pragma unroll
            for (int ii = 0; ii < 8; ++ii)
#pragma unroll
                for (int jj = 0; jj < 8; ++jj)
                    c[ii][jj] = fmaf(av[ii], bv[jj], c[ii][jj]);
        }
        if (pf) {
            va.x = fmaxf(fmaf(va.x, scA, shA), 0.f);
            va.y = fmaxf(fmaf(va.y, scA, shA), 0.f);
            va.z = fmaxf(fmaf(va.z, scA, shA), 0.f);
            va.w = fmaxf(fmaf(va.w, scA, shA), 0.f);
            rsum += va.x + va.y + va.z + va.w;
            asT[cur ^ 1][ajq * 4 + 0][ai] = va.x;
            asT[cur ^ 1][ajq * 4 + 1][ai] = va.y;
            asT[cur ^ 1][ajq * 4 + 2][ai] = va.z;
            asT[cur ^ 1][ajq * 4 + 3][ai] = va.w;
        }
        __syncthreads();
        cur ^= 1;
    }
    // rowsum partial: reduce over the 8 lanes sharing row ai
    rsum += __shfl_down(rsum, 4, 8);
    rsum += __shfl_down(rsum, 2, 8);
    rsum += __shfl_down(rsum, 1, 8);
    if ((t & 7) == 0) atomicAdd(&stats[O_RS + b * 32 + ai], rsum);
    // write partials (atomic-free)
#pragma unroll
    for (int ii = 0; ii < 8; ++ii) {
        float* dst = part + ((size_t)sp * 2048 + b * 32 + ty * 8 + ii) * 512;
        float4 r0 = {c[ii][0], c[ii][1], c[ii][2], c[ii][3]};
        float4 r1 = {c[ii][4], c[ii][5], c[ii][6], c[ii][7]};
        F4(dst + tx * 4) = r0;
        F4(dst + 256 + tx * 4) = r1;
    }
}

// out[row][d] = (sum_s part[s][row][d]) / (rs[row]+eps)
__global__ void k_finout(const float* __restrict__ part, const float* __restrict__ stats,
                         float* __restrict__ out) {
    int f = blockIdx.x * 256 + threadIdx.x;   // 262144 float4
    int row = f >> 7;
    float4 v0 = CF4(part + (size_t)f * 4);
    float4 v1 = CF4(part + 1048576 + (size_t)f * 4);
    float4 v2 = CF4(part + 2097152 + (size_t)f * 4);
    float4 v3 = CF4(part + 3145728 + (size_t)f * 4);
    float inv = 1.0f / (stats[O_RS + row] + 1e-12f);
    float4 o = {(v0.x + v1.x + v2.x + v3.x) * inv,
                (v0.y + v1.y + v2.y + v3.y) * inv,
                (v0.z + v1.z + v2.z + v3.z) * inv,
                (v0.w + v1.w + v2.w + v3.w) * inv};
    F4(out + (size_t)f * 4) = o;
}

extern "C" void kernel_launch(void* const* d_in, const int* in_sizes, int n_in,
                              void* d_out, int out_size, void* d_ws, size_t ws_size,
                              hipStream_t stream) {
    const float* x    = (const float*)d_in[0];
    const float* meta = (const float*)d_in[1];
    const float* Wq   = (const float*)d_in[2];
    const float* bq   = (const float*)d_in[3];
    const float* g1   = (const float*)d_in[4];
    const float* b1   = (const float*)d_in[5];
    const float* g2   = (const float*)d_in[6];
    const float* b2   = (const float*)d_in[7];
    float* out = (float*)d_out;

    float* ws = (float*)d_ws;
    float* slots = ws;                  // 1,048,576 floats
    float* q     = ws + 1048576;        // 1,048,576
    float* attn  = ws + 2097152;        // 8,388,608
    float* stats = ws + 10485760;       // 4,224
    float* part  = ws + 10489984;       // 4 x 1,048,576 = 4,194,304
    float* wqT   = ws + 14684288;       // 262,144
    float* xT    = ws + 16777216;       // 134,217,728

    // one-time transposes
    k_transpose64<<<dim3(8, 8, 1), 256, 0, stream>>>(Wq, wqT, 512, 512);
    k_transpose64<<<dim3(64, 8, 64), 256, 0, stream>>>(x, xT, 512, 4096);

    k_init_slots<<<1024, 256, 0, stream>>>(meta, slots);
    for (int it = 0; it < 3; ++it) {
        if (it > 0) k_blend<<<1024, 256, 0, stream>>>(slots, out);
        k_zero_stats<<<1, 256, 0, stream>>>(stats);
        k_qgemm<<<dim3(128, 2), 256, 0, stream>>>(slots, wqT, bq, q, stats);
        k_bn1_fin<<<1, 512, 0, stream>>>(stats, g1, b1);
        k_gemm1<<<dim3(8, 64), 256, 0, stream>>>(q, x, stats, attn);
        k_bn2_fin<<<1, 256, 0, stream>>>(stats, g2, b2);
        k_gemm2<<<dim3(4, 64), 256, 0, stream>>>(attn, xT, stats, part);
        k_finout<<<1024, 256, 0, stream>>>(part, stats, out);
    }
}